// Round 14
// baseline (1167.002 us; speedup 1.0000x reference)
//
#include <hip/hip_runtime.h>

constexpr int N = 100000;
constexpr int E = 1280000;
constexpr int C = 64;
constexpr int NB = (N + 255) / 256;   // 391 dst-buckets of 256 nodes
constexpr int EPB = 4096;             // edges per chist block
constexpr int NBIN = (E + EPB - 1) / EPB;   // 313
constexpr int EPB2 = 8192;            // edges per bin_k block
constexpr int NBIN2 = (E + EPB2 - 1) / EPB2; // 157

typedef __attribute__((ext_vector_type(8))) short bf16x8;
typedef __attribute__((ext_vector_type(4))) float f32x4;

// ---- bf16 helpers (RNE pack, bit-trick unpack) ----
__device__ __forceinline__ unsigned bfr(float v) {
    unsigned u = __float_as_uint(v);
    return (u + 0x7fffu + ((u >> 16) & 1u)) >> 16;
}
__device__ __forceinline__ float bflo(unsigned w) { return __uint_as_float(w << 16); }
__device__ __forceinline__ float bfhi(unsigned w) { return __uint_as_float(w & 0xffff0000u); }

// native LDS fp32 atomic add (HIP's atomicAdd on LDS float compiles to a CAS
// loop - R10 measured 10x slow; ds_add_f32 is the HW instruction).
// DS address operand = low 32 bits of the flat shared address (= LDS byte
// offset; flat shared addrs are {aperture_hi, offset_lo}).
__device__ __forceinline__ void lds_fadd(float* p, float v) {
    unsigned a = (unsigned)(size_t)p;
    asm volatile("ds_add_f32 %0, %1" :: "v"(a), "v"(v));
}

// ---------------- fused prep: cast x | cast W1 | cast W2 | coarse hist ----------------
constexpr int CASTB = (N * 16 + 255) / 256;   // 6250
constexpr int WCB = 8;   // blocks per weight table: 8*256 = 2048 = 64 rows x 32 uint-pairs
__global__ __launch_bounds__(256) void prep_k(
    const float* __restrict__ x, uint2* __restrict__ xb,
    const float* __restrict__ W1l, const float* __restrict__ W1r, unsigned* __restrict__ Wb1,
    const float* __restrict__ W2l, const float* __restrict__ W2r, unsigned* __restrict__ Wb2,
    const int* __restrict__ dst, int* __restrict__ bcnt) {
    int blk = blockIdx.x;
    int t = threadIdx.x;
    if (blk < CASTB) {                         // ---- cast x -> bf16 ----
        int i = blk * 256 + t;
        if (i < N * 16) {
            float4 v = ((const float4*)x)[i];
            uint2 o;
            o.x = bfr(v.x) | (bfr(v.y) << 16);
            o.y = bfr(v.z) | (bfr(v.w) << 16);
            xb[i] = o;
        }
        return;
    }
    if (blk < CASTB + 2 * WCB) {               // ---- cast weights (2048 items each) ----
        int wb = blk - CASTB;                  // 0..15
        const float* Wl = (wb < WCB) ? W1l : W2l;
        const float* Wr = (wb < WCB) ? W1r : W2r;
        unsigned* Wb = (wb < WCB) ? Wb1 : Wb2;
        int u = ((wb < WCB) ? wb : wb - WCB) * 256 + t;   // 0..2047
        int c = u >> 5;        // row 0..63
        int p = u & 31;        // uint-pair 0..31 within the 64-k half
        float2 l = *(const float2*)(Wl + c * 64 + p * 2);
        float2 r = *(const float2*)(Wr + c * 64 + p * 2);
        Wb[c * 64 + p]      = bfr(l.x) | (bfr(l.y) << 16);
        Wb[c * 64 + 32 + p] = bfr(r.x) | (bfr(r.y) << 16);
        return;
    }
    // ---- coarse histogram of dst>>8 ----
    __shared__ int h[NB];
    int cb = blk - CASTB - 2 * WCB;
    for (int i = t; i < NB; i += 256) h[i] = 0;
    __syncthreads();
    int e0 = cb * EPB;
    int eEnd = min(e0 + EPB, E);
    for (int e = e0 + t; e < eEnd; e += 256) atomicAdd(&h[dst[e] >> 8], 1);
    __syncthreads();
    for (int i = t; i < NB; i += 256)
        if (h[i]) atomicAdd(&bcnt[i], h[i]);
}

// ---------------- stage 1: scan bucket counts -> bases; zero cursors ----------------
__global__ __launch_bounds__(512) void scanB_k(const int* __restrict__ bcnt,
                                               int* __restrict__ bbase,
                                               int* __restrict__ gcur) {
    __shared__ int s[2][512];
    int t = threadIdx.x;
    int v = (t < NB) ? bcnt[t] : 0;
    s[0][t] = v;
    __syncthreads();
    int p = 0;
    for (int off = 1; off < 512; off <<= 1) {
        int a = s[p][t] + (t >= off ? s[p][t - off] : 0);
        s[p ^ 1][t] = a;
        p ^= 1;
        __syncthreads();
    }
    if (t < NB) { bbase[t] = s[p][t] - v; gcur[t] = 0; }
}

// ---------------- stage 2: bin edges into bucket-contiguous packed runs ----------------
// packed tmp entry: (src << 8) | (dst & 255)    [src < 2^17 fits bits 8..24]
__global__ __launch_bounds__(512) void bin_k(const int* __restrict__ src,
                                             const int* __restrict__ dst,
                                             const int* __restrict__ bbase,
                                             int* __restrict__ gcur,
                                             unsigned* __restrict__ tmp) {
    __shared__ int hist[NB];
    __shared__ int start[NB];
    __shared__ int cnt2[NB];
    __shared__ int gbase[NB];
    __shared__ unsigned pk[EPB2];          // 32 KB
    __shared__ unsigned short bkt[EPB2];   // 16 KB
    __shared__ int sc[2][512];
    int t = threadIdx.x;
    for (int i = t; i < NB; i += 512) { hist[i] = 0; cnt2[i] = 0; }
    __syncthreads();
    int e0 = blockIdx.x * EPB2;
    int eEnd = min(e0 + EPB2, E);
    for (int e = e0 + t; e < eEnd; e += 512) atomicAdd(&hist[dst[e] >> 8], 1);
    __syncthreads();
    int v = (t < NB) ? hist[t] : 0;
    sc[0][t] = v;
    __syncthreads();
    int p = 0;
    for (int off = 1; off < 512; off <<= 1) {
        int a = sc[p][t] + (t >= off ? sc[p][t - off] : 0);
        sc[p ^ 1][t] = a;
        p ^= 1;
        __syncthreads();
    }
    if (t < NB) start[t] = sc[p][t] - v;
    __syncthreads();
    for (int e = e0 + t; e < eEnd; e += 512) {
        int d = dst[e];
        int b = d >> 8;
        int pos = start[b] + atomicAdd(&cnt2[b], 1);
        pk[pos] = ((unsigned)src[e] << 8) | (unsigned)(d & 255);
        bkt[pos] = (unsigned short)b;
    }
    __syncthreads();
    for (int i = t; i < NB; i += 512)
        gbase[i] = hist[i] ? bbase[i] + atomicAdd(&gcur[i], hist[i]) : 0;
    __syncthreads();
    int n = eEnd - e0;
    for (int i = t; i < n; i += 512) {
        int b = bkt[i];
        tmp[gbase[b] + (i - start[b])] = pk[i];
    }
}

// ------- fused bucket aggregate + combine: one block per 256-node bucket -------
// Phase A: flat edge-parallel over the bucket's tmp run; 4 edge-groups x 16
//   lanes x uint2 gather; 4x ds_add_f32 into sAcc[dl][ch] + ds_add_u32 count.
// Phase B: 64 MFMA units (16 tiles x 4 col-tiles) over 8 waves; A-frags from
//   sAcc*(1/cnt) packed to bf16; root from Fb; B from Wb.  R13-verified
//   fragment mapping and epilogue.
template <int RELU, int OBF>
__global__ __launch_bounds__(512) void aggcomb_k(
    const unsigned* __restrict__ tmp, const int* __restrict__ bbase,
    const int* __restrict__ bcnt,
    const unsigned short* __restrict__ Fb,   // [N][64] bf16 input features
    const unsigned short* __restrict__ Wb,   // [64][128] bf16 (Wl|Wr rows)
    const float* __restrict__ bias,
    float* __restrict__ outF, unsigned short* __restrict__ outB) {
    constexpr int PAD = 69;                  // 69%32=5 -> ~2-way banks both phases
    __shared__ float sAcc[256][PAD];         // 70.7 KB
    __shared__ int sCnt[256];
    int b = blockIdx.x;
    int base = bbase[b];
    int end = base + bcnt[b];
    int t = threadIdx.x;
    for (int i = t; i < 256 * PAD; i += 512) ((float*)sAcc)[i] = 0.f;
    if (t < 256) sCnt[t] = 0;
    __syncthreads();

    int w = t >> 6;
    int lane = t & 63;
    int g = lane >> 4;            // edge group / k-chunk 0..3
    int q = lane & 15;            // channel quad / row / col

    // ---- phase A: edge-parallel aggregation ----
    int i = base + w * 4 + g;
    for (; i + 32 < end; i += 64) {           // 2 edges per group per iter
        unsigned e0 = tmp[i];
        unsigned e1 = tmp[i + 32];
        uint2 u0 = ((const uint2*)Fb)[(size_t)(e0 >> 8) * 16 + q];
        uint2 u1 = ((const uint2*)Fb)[(size_t)(e1 >> 8) * 16 + q];
        int d0 = (int)(e0 & 255u);
        int d1 = (int)(e1 & 255u);
        lds_fadd(&sAcc[d0][q * 4 + 0], bflo(u0.x));
        lds_fadd(&sAcc[d0][q * 4 + 1], bfhi(u0.x));
        lds_fadd(&sAcc[d0][q * 4 + 2], bflo(u0.y));
        lds_fadd(&sAcc[d0][q * 4 + 3], bfhi(u0.y));
        lds_fadd(&sAcc[d1][q * 4 + 0], bflo(u1.x));
        lds_fadd(&sAcc[d1][q * 4 + 1], bfhi(u1.x));
        lds_fadd(&sAcc[d1][q * 4 + 2], bflo(u1.y));
        lds_fadd(&sAcc[d1][q * 4 + 3], bfhi(u1.y));
        if (q == 0) { atomicAdd(&sCnt[d0], 1); atomicAdd(&sCnt[d1], 1); }
    }
    for (; i < end; i += 32) {
        unsigned e0 = tmp[i];
        uint2 u0 = ((const uint2*)Fb)[(size_t)(e0 >> 8) * 16 + q];
        int d0 = (int)(e0 & 255u);
        lds_fadd(&sAcc[d0][q * 4 + 0], bflo(u0.x));
        lds_fadd(&sAcc[d0][q * 4 + 1], bfhi(u0.x));
        lds_fadd(&sAcc[d0][q * 4 + 2], bflo(u0.y));
        lds_fadd(&sAcc[d0][q * 4 + 3], bfhi(u0.y));
        if (q == 0) atomicAdd(&sCnt[d0], 1);
    }
    __syncthreads();

    // ---- phase B: 64 MFMA units over 8 waves ----
    int bucketBase = b * 256;
    for (int u = w; u < 64; u += 8) {
        int tileBase = bucketBase + (u >> 2) * 16;
        if (tileBase >= N) break;             // bucket 390: tiles 10..15 empty
        int ct = u & 3;
        int row = (u >> 2) * 16 + q;          // local row in bucket
        int node = tileBase + q;
        float cn = (float)sCnt[row];
        float inv = cn > 0.f ? 1.f / cn : 0.f;
        const float* ap = sAcc[row];
        bf16x8 a0, a1;
#pragma unroll
        for (int j = 0; j < 8; ++j) {
            a0[j] = (short)bfr(ap[g * 8 + j] * inv);
            a1[j] = (short)bfr(ap[32 + g * 8 + j] * inv);
        }
        const unsigned short* xrow = Fb + (size_t)node * 64 + g * 8;
        bf16x8 a2 = *(const bf16x8*)(const void*)xrow;
        bf16x8 a3 = *(const bf16x8*)(const void*)(xrow + 32);

        int c = ct * 16 + q;
        const unsigned short* wrow = Wb + (size_t)c * 128 + g * 8;
        f32x4 acc = {0.f, 0.f, 0.f, 0.f};
        acc = __builtin_amdgcn_mfma_f32_16x16x32_bf16(a0, *(const bf16x8*)(const void*)(wrow), acc, 0, 0, 0);
        acc = __builtin_amdgcn_mfma_f32_16x16x32_bf16(a1, *(const bf16x8*)(const void*)(wrow + 32), acc, 0, 0, 0);
        acc = __builtin_amdgcn_mfma_f32_16x16x32_bf16(a2, *(const bf16x8*)(const void*)(wrow + 64), acc, 0, 0, 0);
        acc = __builtin_amdgcn_mfma_f32_16x16x32_bf16(a3, *(const bf16x8*)(const void*)(wrow + 96), acc, 0, 0, 0);

        float bs = bias[c];
#pragma unroll
        for (int rr = 0; rr < 4; ++rr) {
            int orow = tileBase + g * 4 + rr;
            float v = acc[rr] + bs;
            if (RELU) v = fmaxf(v, 0.f);
            if (OBF) {
                float v1 = __shfl_xor(v, 1);    // neighbor column's value
                if ((lane & 1) == 0) {
                    unsigned uo = bfr(v) | (bfr(v1) << 16);
                    *(unsigned*)(void*)(outB + (size_t)orow * 64 + c) = uo;
                }
            } else {
                outF[(size_t)orow * 64 + c] = v;
            }
        }
    }
}

extern "C" void kernel_launch(void* const* d_in, const int* in_sizes, int n_in,
                              void* d_out, int out_size, void* d_ws, size_t ws_size,
                              hipStream_t stream) {
    const float* x   = (const float*)d_in[0];
    const int*   ei  = (const int*)d_in[1];
    const int*   srcI = ei;
    const int*   dstI = ei + E;
    const float* W1l = (const float*)d_in[2];
    const float* b1  = (const float*)d_in[3];
    const float* W1r = (const float*)d_in[4];
    const float* W2l = (const float*)d_in[5];
    const float* b2  = (const float*)d_in[6];
    const float* W2r = (const float*)d_in[7];
    float* out = (float*)d_out;

    // workspace layout (4B units)
    int*            bcnt  = (int*)d_ws;                    // 512
    int*            bbase = bcnt + 512;                    // 512
    int*            gcur  = bbase + 512;                   // 512
    unsigned*       tmp   = (unsigned*)(gcur + 512);       // E (5.12 MB, persistent)
    unsigned short* xb    = (unsigned short*)(tmp + E);    // N*64 bf16 (12.8 MB)
    unsigned short* hb    = xb + (size_t)N * 64;           // N*64 bf16
    unsigned*       Wb1   = (unsigned*)(hb + (size_t)N * 64);  // 16 KB
    unsigned*       Wb2   = Wb1 + 64 * 64;                     // 16 KB

    hipMemsetAsync(bcnt, 0, 512 * sizeof(int), stream);

    prep_k<<<CASTB + 2 * WCB + NBIN, 256, 0, stream>>>(
        x, (uint2*)xb, W1l, W1r, Wb1, W2l, W2r, Wb2, dstI, bcnt);
    scanB_k<<<1, 512, 0, stream>>>(bcnt, bbase, gcur);
    bin_k<<<NBIN2, 512, 0, stream>>>(srcI, dstI, bbase, gcur, tmp);

    // ---- layer 1: h = relu(sage(xb)) -> bf16 hb ----
    aggcomb_k<1, 1><<<NB, 512, 0, stream>>>(
        tmp, bbase, bcnt, xb, (const unsigned short*)Wb1, b1, nullptr, hb);

    // ---- layer 2: out = sage(hb) -> fp32 ----
    aggcomb_k<0, 0><<<NB, 512, 0, stream>>>(
        tmp, bbase, bcnt, hb, (const unsigned short*)Wb2, b2, out, nullptr);
}

// Round 15
// 183.014 us; speedup vs baseline: 6.3766x; 6.3766x over previous
//
#include <hip/hip_runtime.h>

constexpr int N = 100000;
constexpr int E = 1280000;
constexpr int C = 64;
constexpr int NB = (N + 255) / 256;   // 391 dst-buckets of 256 nodes
constexpr int EPB = 4096;             // edges per chist block
constexpr int NBIN = (E + EPB - 1) / EPB;   // 313
constexpr int EPB2 = 8192;            // edges per bin_k block
constexpr int NBIN2 = (E + EPB2 - 1) / EPB2; // 157
constexpr int CAP = 4096;             // bucket capacity (avg 3274, max ~3.6k)

typedef __attribute__((ext_vector_type(8))) short bf16x8;
typedef __attribute__((ext_vector_type(4))) float f32x4;

// ---- bf16 helpers (RNE pack, bit-trick unpack) ----
__device__ __forceinline__ unsigned bfr(float v) {
    unsigned u = __float_as_uint(v);
    return (u + 0x7fffu + ((u >> 16) & 1u)) >> 16;
}
__device__ __forceinline__ float bflo(unsigned w) { return __uint_as_float(w << 16); }
__device__ __forceinline__ float bfhi(unsigned w) { return __uint_as_float(w & 0xffff0000u); }

// ---------------- fused prep: cast x | cast W1 | cast W2 | coarse hist ----------------
constexpr int CASTB = (N * 16 + 255) / 256;   // 6250
constexpr int WCB = 8;   // blocks per weight table: 8*256 = 2048 = 64 rows x 32 uint-pairs
__global__ __launch_bounds__(256) void prep_k(
    const float* __restrict__ x, uint2* __restrict__ xb,
    const float* __restrict__ W1l, const float* __restrict__ W1r, unsigned* __restrict__ Wb1,
    const float* __restrict__ W2l, const float* __restrict__ W2r, unsigned* __restrict__ Wb2,
    const int* __restrict__ dst, int* __restrict__ bcnt) {
    int blk = blockIdx.x;
    int t = threadIdx.x;
    if (blk < CASTB) {                         // ---- cast x -> bf16 ----
        int i = blk * 256 + t;
        if (i < N * 16) {
            float4 v = ((const float4*)x)[i];
            uint2 o;
            o.x = bfr(v.x) | (bfr(v.y) << 16);
            o.y = bfr(v.z) | (bfr(v.w) << 16);
            xb[i] = o;
        }
        return;
    }
    if (blk < CASTB + 2 * WCB) {               // ---- cast weights (2048 items each) ----
        int wb = blk - CASTB;                  // 0..15
        const float* Wl = (wb < WCB) ? W1l : W2l;
        const float* Wr = (wb < WCB) ? W1r : W2r;
        unsigned* Wb = (wb < WCB) ? Wb1 : Wb2;
        int u = ((wb < WCB) ? wb : wb - WCB) * 256 + t;   // 0..2047
        int c = u >> 5;        // row 0..63
        int p = u & 31;        // uint-pair 0..31 within the 64-k half
        float2 l = *(const float2*)(Wl + c * 64 + p * 2);
        float2 r = *(const float2*)(Wr + c * 64 + p * 2);
        Wb[c * 64 + p]      = bfr(l.x) | (bfr(l.y) << 16);
        Wb[c * 64 + 32 + p] = bfr(r.x) | (bfr(r.y) << 16);
        return;
    }
    // ---- coarse histogram of dst>>8 ----
    __shared__ int h[NB];
    int cb = blk - CASTB - 2 * WCB;
    for (int i = t; i < NB; i += 256) h[i] = 0;
    __syncthreads();
    int e0 = cb * EPB;
    int eEnd = min(e0 + EPB, E);
    for (int e = e0 + t; e < eEnd; e += 256) atomicAdd(&h[dst[e] >> 8], 1);
    __syncthreads();
    for (int i = t; i < NB; i += 256)
        if (h[i]) atomicAdd(&bcnt[i], h[i]);
}

// ---------------- stage 1: scan bucket counts -> bases; zero cursors ----------------
__global__ __launch_bounds__(512) void scanB_k(const int* __restrict__ bcnt,
                                               int* __restrict__ bbase,
                                               int* __restrict__ gcur) {
    __shared__ int s[2][512];
    int t = threadIdx.x;
    int v = (t < NB) ? bcnt[t] : 0;
    s[0][t] = v;
    __syncthreads();
    int p = 0;
    for (int off = 1; off < 512; off <<= 1) {
        int a = s[p][t] + (t >= off ? s[p][t - off] : 0);
        s[p ^ 1][t] = a;
        p ^= 1;
        __syncthreads();
    }
    if (t < NB) { bbase[t] = s[p][t] - v; gcur[t] = 0; }
}

// ---------------- stage 2: bin edges into bucket-contiguous packed runs ----------------
// packed tmp entry: (src << 8) | (dst & 255)    [src < 2^17 fits bits 8..24]
__global__ __launch_bounds__(512) void bin_k(const int* __restrict__ src,
                                             const int* __restrict__ dst,
                                             const int* __restrict__ bbase,
                                             int* __restrict__ gcur,
                                             unsigned* __restrict__ tmp) {
    __shared__ int hist[NB];
    __shared__ int start[NB];
    __shared__ int cnt2[NB];
    __shared__ int gbase[NB];
    __shared__ unsigned pk[EPB2];          // 32 KB
    __shared__ unsigned short bkt[EPB2];   // 16 KB
    __shared__ int sc[2][512];
    int t = threadIdx.x;
    for (int i = t; i < NB; i += 512) { hist[i] = 0; cnt2[i] = 0; }
    __syncthreads();
    int e0 = blockIdx.x * EPB2;
    int eEnd = min(e0 + EPB2, E);
    for (int e = e0 + t; e < eEnd; e += 512) atomicAdd(&hist[dst[e] >> 8], 1);
    __syncthreads();
    int v = (t < NB) ? hist[t] : 0;
    sc[0][t] = v;
    __syncthreads();
    int p = 0;
    for (int off = 1; off < 512; off <<= 1) {
        int a = sc[p][t] + (t >= off ? sc[p][t - off] : 0);
        sc[p ^ 1][t] = a;
        p ^= 1;
        __syncthreads();
    }
    if (t < NB) start[t] = sc[p][t] - v;
    __syncthreads();
    for (int e = e0 + t; e < eEnd; e += 512) {
        int d = dst[e];
        int b = d >> 8;
        int pos = start[b] + atomicAdd(&cnt2[b], 1);
        pk[pos] = ((unsigned)src[e] << 8) | (unsigned)(d & 255);
        bkt[pos] = (unsigned short)b;
    }
    __syncthreads();
    for (int i = t; i < NB; i += 512)
        gbase[i] = hist[i] ? bbase[i] + atomicAdd(&gcur[i], hist[i]) : 0;
    __syncthreads();
    int n = eEnd - e0;
    for (int i = t; i < n; i += 512) {
        int b = bkt[i];
        tmp[gbase[b] + (i - start[b])] = pk[i];
    }
}

// ---------------- stage 3: per-bucket counting sort -> rowp/deg/csr ----------------
__global__ __launch_bounds__(512) void bsort_k(const unsigned* __restrict__ tmp,
                                               const int* __restrict__ bbase,
                                               const int* __restrict__ bcnt,
                                               int* __restrict__ rowp,
                                               int* __restrict__ deg,
                                               int* __restrict__ csr) {
    int b = blockIdx.x;
    int base = bbase[b];
    int count = bcnt[b];
    __shared__ int h[256], st[256], c2[256];
    __shared__ int sc[2][256];
    __shared__ unsigned srcA[CAP];   // 16 KB
    int t = threadIdx.x;
    if (t < 256) { h[t] = 0; c2[t] = 0; }
    __syncthreads();
    for (int i = t; i < count; i += 512) atomicAdd(&h[tmp[base + i] & 255u], 1);
    __syncthreads();
    if (t < 256) sc[0][t] = h[t];
    __syncthreads();
    int p = 0;
    for (int off = 1; off < 256; off <<= 1) {
        if (t < 256) sc[p ^ 1][t] = sc[p][t] + (t >= off ? sc[p][t - off] : 0);
        p ^= 1;
        __syncthreads();
    }
    if (t < 256) {
        int excl = sc[p][t] - h[t];
        st[t] = excl;
        int node = b * 256 + t;
        if (node < N) { rowp[node] = base + excl; deg[node] = h[t]; }
    }
    __syncthreads();
    for (int i = t; i < count; i += 512) {
        unsigned pr = tmp[base + i];
        int d = (int)(pr & 255u);
        int pos = st[d] + atomicAdd(&c2[d], 1);
        srcA[pos] = pr >> 8;
    }
    __syncthreads();
    for (int i = t; i < count; i += 512) csr[base + i] = (int)srcA[i];
}

// ------- fused aggregate + combine, wave-private: one WAVE per 16-node tile -------
// Phase A: wave aggregates its 16 nodes (R12-proven loop, 16 serial node-loops),
//   packs bf16 mean rows into its own LDS quadrant sT[w][16][72]. No barrier:
//   same-wave ds_write -> ds_read needs only lgkmcnt (compiler-inserted).
// Phase B: R7-proven per-wave combine: 4 col-tiles x 4 MFMA; A-frags from
//   sT[w] (agg) + global Fb (root); B-frags from Wb; verified C/D epilogue.
template <int RELU, int OBF>
__global__ __launch_bounds__(256) void aggcomb_k(
    const int* __restrict__ csr, const int* __restrict__ rowp,
    const int* __restrict__ deg,
    const unsigned short* __restrict__ Fb,   // [N][64] bf16 input features
    const unsigned short* __restrict__ Wb,   // [64][128] bf16 (Wl|Wr rows)
    const float* __restrict__ bias,
    float* __restrict__ outF, unsigned short* __restrict__ outB) {
    __shared__ unsigned short sT[4][16][72];   // 9216 B; row stride 144B -> 2-way banks
    const uint2* featb = (const uint2*)Fb;
    int w = threadIdx.x >> 6;
    int lane = threadIdx.x & 63;
    int g = lane >> 4;            // edge slot / k-chunk 0..3
    int q = lane & 15;            // channel quad / tile row / col row

    int tileIdx = blockIdx.x * 4 + w;
    if (tileIdx >= N / 16) return;            // N/16 = 6250 exact
    int tile = tileIdx * 16;

    // ---- phase A: aggregate 16 nodes (wave-serial over nodes, 4x16 lanes each) ----
    for (int s = 0; s < 16; ++s) {
        int node = tile + s;
        int start = rowp[node];
        int d = deg[node];
        float4 acc = make_float4(0.f, 0.f, 0.f, 0.f);
        int j = g;
        for (; j + 4 < d; j += 8) {           // 8 edges in flight per wave
            int s0 = csr[start + j];
            int s1 = csr[start + j + 4];
            uint2 u0 = featb[(size_t)s0 * 16 + q];
            uint2 u1 = featb[(size_t)s1 * 16 + q];
            acc.x += bflo(u0.x) + bflo(u1.x);
            acc.y += bfhi(u0.x) + bfhi(u1.x);
            acc.z += bflo(u0.y) + bflo(u1.y);
            acc.w += bfhi(u0.y) + bfhi(u1.y);
        }
        for (; j < d; j += 4) {
            int s0 = csr[start + j];
            uint2 u0 = featb[(size_t)s0 * 16 + q];
            acc.x += bflo(u0.x); acc.y += bfhi(u0.x);
            acc.z += bflo(u0.y); acc.w += bfhi(u0.y);
        }
#pragma unroll
        for (int off = 16; off <= 32; off <<= 1) {
            acc.x += __shfl_xor(acc.x, off);
            acc.y += __shfl_xor(acc.y, off);
            acc.z += __shfl_xor(acc.z, off);
            acc.w += __shfl_xor(acc.w, off);
        }
        if (g == 0) {
            float inv = d > 0 ? 1.f / (float)d : 0.f;
            uint2 o;
            o.x = bfr(acc.x * inv) | (bfr(acc.y * inv) << 16);
            o.y = bfr(acc.z * inv) | (bfr(acc.w * inv) << 16);
            *(uint2*)&sT[w][s][q * 4] = o;
        }
    }

    // ---- phase B: this wave's 16x64 combine (no barrier: same-wave LDS) ----
    int r = q;
    int node = tile + r;
    const unsigned short* xrow = Fb + (size_t)node * 64 + g * 8;
    bf16x8 a[4];
    a[0] = *(const bf16x8*)(const void*)&sT[w][r][g * 8];
    a[1] = *(const bf16x8*)(const void*)&sT[w][r][32 + g * 8];
    a[2] = *(const bf16x8*)(const void*)(xrow);
    a[3] = *(const bf16x8*)(const void*)(xrow + 32);

#pragma unroll
    for (int ct = 0; ct < 4; ++ct) {
        int c = ct * 16 + r;
        const unsigned short* wrow = Wb + (size_t)c * 128 + g * 8;
        f32x4 acc = {0.f, 0.f, 0.f, 0.f};
#pragma unroll
        for (int kc = 0; kc < 4; ++kc) {
            bf16x8 b = *(const bf16x8*)(const void*)(wrow + kc * 32);
            acc = __builtin_amdgcn_mfma_f32_16x16x32_bf16(a[kc], b, acc, 0, 0, 0);
        }
        float bs = bias[c];
#pragma unroll
        for (int rr = 0; rr < 4; ++rr) {
            int orow = tile + g * 4 + rr;
            float v = acc[rr] + bs;
            if (RELU) v = fmaxf(v, 0.f);
            if (OBF) {
                float v1 = __shfl_xor(v, 1);    // neighbor column's value
                if ((lane & 1) == 0) {
                    unsigned u = bfr(v) | (bfr(v1) << 16);
                    *(unsigned*)(void*)(outB + (size_t)orow * 64 + c) = u;
                }
            } else {
                outF[(size_t)orow * 64 + c] = v;
            }
        }
    }
}

extern "C" void kernel_launch(void* const* d_in, const int* in_sizes, int n_in,
                              void* d_out, int out_size, void* d_ws, size_t ws_size,
                              hipStream_t stream) {
    const float* x   = (const float*)d_in[0];
    const int*   ei  = (const int*)d_in[1];
    const int*   srcI = ei;
    const int*   dstI = ei + E;
    const float* W1l = (const float*)d_in[2];
    const float* b1  = (const float*)d_in[3];
    const float* W1r = (const float*)d_in[4];
    const float* W2l = (const float*)d_in[5];
    const float* b2  = (const float*)d_in[6];
    const float* W2r = (const float*)d_in[7];
    float* out = (float*)d_out;

    // workspace layout (4B units)
    int*            bcnt  = (int*)d_ws;                    // 512
    int*            bbase = bcnt + 512;                    // 512
    int*            gcur  = bbase + 512;                   // 512
    int*            deg   = gcur + 512;                    // 102400
    int*            rowp  = deg + 102400;                  // 102400
    int*            csr   = rowp + 102400;                 // E
    unsigned*       tmp   = (unsigned*)(csr + E);          // E (5.12 MB)
    unsigned short* xb    = (unsigned short*)(tmp + E);    // N*64 bf16 (12.8 MB)
    unsigned short* hb    = xb + (size_t)N * 64;           // N*64 bf16
    unsigned*       Wb1   = (unsigned*)(hb + (size_t)N * 64);  // 16 KB
    unsigned*       Wb2   = Wb1 + 64 * 64;                     // 16 KB

    hipMemsetAsync(bcnt, 0, 512 * sizeof(int), stream);

    prep_k<<<CASTB + 2 * WCB + NBIN, 256, 0, stream>>>(
        x, (uint2*)xb, W1l, W1r, Wb1, W2l, W2r, Wb2, dstI, bcnt);
    scanB_k<<<1, 512, 0, stream>>>(bcnt, bbase, gcur);
    bin_k<<<NBIN2, 512, 0, stream>>>(srcI, dstI, bbase, gcur, tmp);
    bsort_k<<<NB, 512, 0, stream>>>(tmp, bbase, bcnt, rowp, deg, csr);

    const int nTileBlocks = (N / 16 + 3) / 4;   // 1563 blocks x 4 waves

    // ---- layer 1: h = relu(sage(xb)) -> bf16 hb ----
    aggcomb_k<1, 1><<<nTileBlocks, 256, 0, stream>>>(
        csr, rowp, deg, xb, (const unsigned short*)Wb1, b1, nullptr, hb);

    // ---- layer 2: out = sage(hb) -> fp32 ----
    aggcomb_k<0, 0><<<nTileBlocks, 256, 0, stream>>>(
        csr, rowp, deg, hb, (const unsigned short*)Wb2, b2, out, nullptr);
}

// Round 16
// 159.317 us; speedup vs baseline: 7.3250x; 1.1487x over previous
//
#include <hip/hip_runtime.h>

constexpr int N = 100000;
constexpr int E = 1280000;
constexpr int C = 64;
constexpr int NB = (N + 255) / 256;   // 391 dst-buckets of 256 nodes
constexpr int EPB = 4096;             // edges per chist block
constexpr int NBIN = (E + EPB - 1) / EPB;   // 313
constexpr int EPB2 = 8192;            // edges per bin_k block
constexpr int NBIN2 = (E + EPB2 - 1) / EPB2; // 157
constexpr int CAP = 4096;             // bucket capacity (avg 3274, max ~3.6k)

typedef __attribute__((ext_vector_type(8))) short bf16x8;
typedef __attribute__((ext_vector_type(4))) float f32x4;

// ---- bf16 helpers (RNE pack, bit-trick unpack) ----
__device__ __forceinline__ unsigned bfr(float v) {
    unsigned u = __float_as_uint(v);
    return (u + 0x7fffu + ((u >> 16) & 1u)) >> 16;
}
__device__ __forceinline__ float bflo(unsigned w) { return __uint_as_float(w << 16); }
__device__ __forceinline__ float bfhi(unsigned w) { return __uint_as_float(w & 0xffff0000u); }

// ---------------- fused prep: cast x | cast W1 | cast W2 | coarse hist ----------------
constexpr int CASTB = (N * 16 + 255) / 256;   // 6250
constexpr int WCB = 8;   // blocks per weight table: 8*256 = 2048 = 64 rows x 32 uint-pairs
__global__ __launch_bounds__(256) void prep_k(
    const float* __restrict__ x, uint2* __restrict__ xb,
    const float* __restrict__ W1l, const float* __restrict__ W1r, unsigned* __restrict__ Wb1,
    const float* __restrict__ W2l, const float* __restrict__ W2r, unsigned* __restrict__ Wb2,
    const int* __restrict__ dst, int* __restrict__ bcnt) {
    int blk = blockIdx.x;
    int t = threadIdx.x;
    if (blk < CASTB) {                         // ---- cast x -> bf16 ----
        int i = blk * 256 + t;
        if (i < N * 16) {
            float4 v = ((const float4*)x)[i];
            uint2 o;
            o.x = bfr(v.x) | (bfr(v.y) << 16);
            o.y = bfr(v.z) | (bfr(v.w) << 16);
            xb[i] = o;
        }
        return;
    }
    if (blk < CASTB + 2 * WCB) {               // ---- cast weights (2048 items each) ----
        int wb = blk - CASTB;                  // 0..15
        const float* Wl = (wb < WCB) ? W1l : W2l;
        const float* Wr = (wb < WCB) ? W1r : W2r;
        unsigned* Wb = (wb < WCB) ? Wb1 : Wb2;
        int u = ((wb < WCB) ? wb : wb - WCB) * 256 + t;   // 0..2047
        int c = u >> 5;        // row 0..63
        int p = u & 31;        // uint-pair 0..31 within the 64-k half
        float2 l = *(const float2*)(Wl + c * 64 + p * 2);
        float2 r = *(const float2*)(Wr + c * 64 + p * 2);
        Wb[c * 64 + p]      = bfr(l.x) | (bfr(l.y) << 16);
        Wb[c * 64 + 32 + p] = bfr(r.x) | (bfr(r.y) << 16);
        return;
    }
    // ---- coarse histogram of dst>>8 ----
    __shared__ int h[NB];
    int cb = blk - CASTB - 2 * WCB;
    for (int i = t; i < NB; i += 256) h[i] = 0;
    __syncthreads();
    int e0 = cb * EPB;
    int eEnd = min(e0 + EPB, E);
    for (int e = e0 + t; e < eEnd; e += 256) atomicAdd(&h[dst[e] >> 8], 1);
    __syncthreads();
    for (int i = t; i < NB; i += 256)
        if (h[i]) atomicAdd(&bcnt[i], h[i]);
}

// ---------------- stage 1: scan bucket counts -> bases; zero cursors ----------------
__global__ __launch_bounds__(512) void scanB_k(const int* __restrict__ bcnt,
                                               int* __restrict__ bbase,
                                               int* __restrict__ gcur) {
    __shared__ int s[2][512];
    int t = threadIdx.x;
    int v = (t < NB) ? bcnt[t] : 0;
    s[0][t] = v;
    __syncthreads();
    int p = 0;
    for (int off = 1; off < 512; off <<= 1) {
        int a = s[p][t] + (t >= off ? s[p][t - off] : 0);
        s[p ^ 1][t] = a;
        p ^= 1;
        __syncthreads();
    }
    if (t < NB) { bbase[t] = s[p][t] - v; gcur[t] = 0; }
}

// ---------------- stage 2: bin edges into bucket-contiguous packed runs ----------------
// packed tmp entry: (src << 8) | (dst & 255)    [src < 2^17 fits bits 8..24]
__global__ __launch_bounds__(512) void bin_k(const int* __restrict__ src,
                                             const int* __restrict__ dst,
                                             const int* __restrict__ bbase,
                                             int* __restrict__ gcur,
                                             unsigned* __restrict__ tmp) {
    __shared__ int hist[NB];
    __shared__ int start[NB];
    __shared__ int cnt2[NB];
    __shared__ int gbase[NB];
    __shared__ unsigned pk[EPB2];          // 32 KB
    __shared__ unsigned short bkt[EPB2];   // 16 KB
    __shared__ int sc[2][512];
    int t = threadIdx.x;
    for (int i = t; i < NB; i += 512) { hist[i] = 0; cnt2[i] = 0; }
    __syncthreads();
    int e0 = blockIdx.x * EPB2;
    int eEnd = min(e0 + EPB2, E);
    for (int e = e0 + t; e < eEnd; e += 512) atomicAdd(&hist[dst[e] >> 8], 1);
    __syncthreads();
    int v = (t < NB) ? hist[t] : 0;
    sc[0][t] = v;
    __syncthreads();
    int p = 0;
    for (int off = 1; off < 512; off <<= 1) {
        int a = sc[p][t] + (t >= off ? sc[p][t - off] : 0);
        sc[p ^ 1][t] = a;
        p ^= 1;
        __syncthreads();
    }
    if (t < NB) start[t] = sc[p][t] - v;
    __syncthreads();
    for (int e = e0 + t; e < eEnd; e += 512) {
        int d = dst[e];
        int b = d >> 8;
        int pos = start[b] + atomicAdd(&cnt2[b], 1);
        pk[pos] = ((unsigned)src[e] << 8) | (unsigned)(d & 255);
        bkt[pos] = (unsigned short)b;
    }
    __syncthreads();
    for (int i = t; i < NB; i += 512)
        gbase[i] = hist[i] ? bbase[i] + atomicAdd(&gcur[i], hist[i]) : 0;
    __syncthreads();
    int n = eEnd - e0;
    for (int i = t; i < n; i += 512) {
        int b = bkt[i];
        tmp[gbase[b] + (i - start[b])] = pk[i];
    }
}

// ---------------- stage 3: per-bucket counting sort -> rowp/deg/csr ----------------
__global__ __launch_bounds__(512) void bsort_k(const unsigned* __restrict__ tmp,
                                               const int* __restrict__ bbase,
                                               const int* __restrict__ bcnt,
                                               int* __restrict__ rowp,
                                               int* __restrict__ deg,
                                               int* __restrict__ csr) {
    int b = blockIdx.x;
    int base = bbase[b];
    int count = bcnt[b];
    __shared__ int h[256], st[256], c2[256];
    __shared__ int sc[2][256];
    __shared__ unsigned srcA[CAP];   // 16 KB
    int t = threadIdx.x;
    if (t < 256) { h[t] = 0; c2[t] = 0; }
    __syncthreads();
    for (int i = t; i < count; i += 512) atomicAdd(&h[tmp[base + i] & 255u], 1);
    __syncthreads();
    if (t < 256) sc[0][t] = h[t];
    __syncthreads();
    int p = 0;
    for (int off = 1; off < 256; off <<= 1) {
        if (t < 256) sc[p ^ 1][t] = sc[p][t] + (t >= off ? sc[p][t - off] : 0);
        p ^= 1;
        __syncthreads();
    }
    if (t < 256) {
        int excl = sc[p][t] - h[t];
        st[t] = excl;
        int node = b * 256 + t;
        if (node < N) { rowp[node] = base + excl; deg[node] = h[t]; }
    }
    __syncthreads();
    for (int i = t; i < count; i += 512) {
        unsigned pr = tmp[base + i];
        int d = (int)(pr & 255u);
        int pos = st[d] + atomicAdd(&c2[d], 1);
        srcA[pos] = pr >> 8;
    }
    __syncthreads();
    for (int i = t; i < count; i += 512) csr[base + i] = (int)srcA[i];
}

// ------- fused aggregate + combine: one block per 16-node tile (R13-proven) -------
// Phase A (per wave w): aggregate nodes tile+w*4+{0..3},
//   pack bf16 mean rows into LDS sAgg[16][72].
// Phase B (per wave w): col-tile ct = w of the 16x64 output:
//   A-frags from sAgg (agg) + global Fb (root), B-frags from Wb; 4 MFMA.
template <int RELU, int OBF>
__global__ __launch_bounds__(256) void aggcomb_k(
    const int* __restrict__ csr, const int* __restrict__ rowp,
    const int* __restrict__ deg,
    const unsigned short* __restrict__ Fb,   // [N][64] bf16 input features
    const unsigned short* __restrict__ Wb,   // [64][128] bf16 (Wl|Wr rows)
    const float* __restrict__ bias,
    float* __restrict__ outF, unsigned short* __restrict__ outB) {
    __shared__ unsigned short sAgg[16][72];
    const uint2* featb = (const uint2*)Fb;
    int tile = blockIdx.x * 16;              // N = 16 * 6250 exact
    int w = threadIdx.x >> 6;
    int lane = threadIdx.x & 63;
    int g = lane >> 4;            // edge slot / k-chunk 0..3
    int q = lane & 15;            // channel quad / tile row

    // ---- phase A: aggregation ----
    for (int s = 0; s < 4; ++s) {
        int node = tile + w * 4 + s;
        int start = rowp[node];
        int d = deg[node];
        float4 acc = make_float4(0.f, 0.f, 0.f, 0.f);
        int j = g;
        for (; j + 4 < d; j += 8) {
            int s0 = csr[start + j];
            int s1 = csr[start + j + 4];
            uint2 u0 = featb[(size_t)s0 * 16 + q];
            uint2 u1 = featb[(size_t)s1 * 16 + q];
            acc.x += bflo(u0.x) + bflo(u1.x);
            acc.y += bfhi(u0.x) + bfhi(u1.x);
            acc.z += bflo(u0.y) + bflo(u1.y);
            acc.w += bfhi(u0.y) + bfhi(u1.y);
        }
        for (; j < d; j += 4) {
            int s0 = csr[start + j];
            uint2 u0 = featb[(size_t)s0 * 16 + q];
            acc.x += bflo(u0.x); acc.y += bfhi(u0.x);
            acc.z += bflo(u0.y); acc.w += bfhi(u0.y);
        }
#pragma unroll
        for (int off = 16; off <= 32; off <<= 1) {
            acc.x += __shfl_xor(acc.x, off);
            acc.y += __shfl_xor(acc.y, off);
            acc.z += __shfl_xor(acc.z, off);
            acc.w += __shfl_xor(acc.w, off);
        }
        if (g == 0) {
            float inv = d > 0 ? 1.f / (float)d : 0.f;
            uint2 o;
            o.x = bfr(acc.x * inv) | (bfr(acc.y * inv) << 16);
            o.y = bfr(acc.z * inv) | (bfr(acc.w * inv) << 16);
            *(uint2*)&sAgg[w * 4 + s][q * 4] = o;
        }
    }
    __syncthreads();

    // ---- phase B: combine (wave w = col-tile w) ----
    int r = q;                    // row within tile = lane & 15
    int node = tile + r;
    const unsigned short* xrow = Fb + (size_t)node * 64 + g * 8;
    bf16x8 a[4];
    a[0] = *(const bf16x8*)(const void*)&sAgg[r][g * 8];
    a[1] = *(const bf16x8*)(const void*)&sAgg[r][32 + g * 8];
    a[2] = *(const bf16x8*)(const void*)(xrow);
    a[3] = *(const bf16x8*)(const void*)(xrow + 32);

    int c = w * 16 + r;
    const unsigned short* wrow = Wb + (size_t)c * 128 + g * 8;
    f32x4 acc = {0.f, 0.f, 0.f, 0.f};
#pragma unroll
    for (int kc = 0; kc < 4; ++kc) {
        bf16x8 b = *(const bf16x8*)(const void*)(wrow + kc * 32);
        acc = __builtin_amdgcn_mfma_f32_16x16x32_bf16(a[kc], b, acc, 0, 0, 0);
    }
    float bs = bias[c];
#pragma unroll
    for (int rr = 0; rr < 4; ++rr) {
        int orow = tile + g * 4 + rr;
        float v = acc[rr] + bs;
        if (RELU) v = fmaxf(v, 0.f);
        if (OBF) {
            float v1 = __shfl_xor(v, 1);    // neighbor column's value
            if ((lane & 1) == 0) {
                unsigned u = bfr(v) | (bfr(v1) << 16);
                *(unsigned*)(void*)(outB + (size_t)orow * 64 + c) = u;
            }
        } else {
            outF[(size_t)orow * 64 + c] = v;
        }
    }
}

extern "C" void kernel_launch(void* const* d_in, const int* in_sizes, int n_in,
                              void* d_out, int out_size, void* d_ws, size_t ws_size,
                              hipStream_t stream) {
    const float* x   = (const float*)d_in[0];
    const int*   ei  = (const int*)d_in[1];
    const int*   srcI = ei;
    const int*   dstI = ei + E;
    const float* W1l = (const float*)d_in[2];
    const float* b1  = (const float*)d_in[3];
    const float* W1r = (const float*)d_in[4];
    const float* W2l = (const float*)d_in[5];
    const float* b2  = (const float*)d_in[6];
    const float* W2r = (const float*)d_in[7];
    float* out = (float*)d_out;

    // workspace layout (4B units)
    int*            bcnt  = (int*)d_ws;                    // 512
    int*            bbase = bcnt + 512;                    // 512
    int*            gcur  = bbase + 512;                   // 512
    int*            deg   = gcur + 512;                    // 102400
    int*            rowp  = deg + 102400;                  // 102400
    int*            csr   = rowp + 102400;                 // E
    unsigned*       tmp   = (unsigned*)(csr + E);          // E (5.12 MB)
    unsigned short* xb    = (unsigned short*)(tmp + E);    // N*64 bf16 (12.8 MB)
    unsigned short* hb    = xb + (size_t)N * 64;           // N*64 bf16
    unsigned*       Wb1   = (unsigned*)(hb + (size_t)N * 64);  // 16 KB
    unsigned*       Wb2   = Wb1 + 64 * 64;                     // 16 KB

    hipMemsetAsync(bcnt, 0, 512 * sizeof(int), stream);

    prep_k<<<CASTB + 2 * WCB + NBIN, 256, 0, stream>>>(
        x, (uint2*)xb, W1l, W1r, Wb1, W2l, W2r, Wb2, dstI, bcnt);
    scanB_k<<<1, 512, 0, stream>>>(bcnt, bbase, gcur);
    bin_k<<<NBIN2, 512, 0, stream>>>(srcI, dstI, bbase, gcur, tmp);
    bsort_k<<<NB, 512, 0, stream>>>(tmp, bbase, bcnt, rowp, deg, csr);

    const int nTileBlocks = N / 16;   // 6250

    // ---- layer 1: h = relu(sage(xb)) -> bf16 hb ----
    aggcomb_k<1, 1><<<nTileBlocks, 256, 0, stream>>>(
        csr, rowp, deg, xb, (const unsigned short*)Wb1, b1, nullptr, hb);

    // ---- layer 2: out = sage(hb) -> fp32 ----
    aggcomb_k<0, 0><<<nTileBlocks, 256, 0, stream>>>(
        csr, rowp, deg, hb, (const unsigned short*)Wb2, b2, out, nullptr);
}